// Round 1
// baseline (3583.080 us; speedup 1.0000x reference)
//
#include <hip/hip_runtime.h>
#include <math.h>

#define Bq 128
#define Tq 128
#define Vq 5000
#define VP 5120
#define Eq 256
#define Hq 512
#define Lq 128
#define G3H 1536
#define KT 128
#define LROW 136

typedef __attribute__((ext_vector_type(8))) short bf16x8;
typedef __attribute__((ext_vector_type(4))) float f32x4;

__device__ __forceinline__ ushort f2bf(float f) {
    union { float f; unsigned u; } v; v.f = f;
    unsigned r = (v.u + 0x7FFFu + ((v.u >> 16) & 1u)) >> 16;
    return (ushort)r;
}
__device__ __forceinline__ float bf2f(ushort s) {
    union { unsigned u; float f; } v; v.u = ((unsigned)s) << 16;
    return v.f;
}

// ---- MFMA tile accumulate, KT=128: acc += A[MI*32 x Klen] * B[128 x Klen]^T ----
// MI=4: wave 64x64. MI=2: wave 32x64. MI=1: wave 16x64 (32 A-rows per block).
template<int MI>
__device__ __forceinline__ void macT(
    f32x4 (&acc)[MI][4],
    const ushort* __restrict__ A, int lda,
    const ushort* __restrict__ Bm, int ldb,
    int n0, int kbase, int Klen,
    ushort* As, ushort* Bs)
{
    const int NA = 2 * MI;
    const int tid = threadIdx.x;
    const int lane = tid & 63;
    const int w = tid >> 6;
    const int wm = (w >> 1) * (MI * 16);
    const int wn = (w & 1) * 64;
    const int fr = lane & 15;
    const int fk = (lane >> 4) * 8;

    int arow[NA], akc[NA];
    #pragma unroll
    for (int i = 0; i < NA; ++i) {
        int c = tid + i * 256;
        arow[i] = c >> 4; akc[i] = (c & 15) * 8;
    }
    int brow[8], bkc[8];
    #pragma unroll
    for (int i = 0; i < 8; ++i) {
        int c = tid + i * 256;
        brow[i] = c >> 4; bkc[i] = (c & 15) * 8;
    }

    const int nk = Klen / KT;
    bf16x8 ra[NA], rb[8];
    #pragma unroll
    for (int i = 0; i < NA; ++i)
        ra[i] = *(const bf16x8*)(A + (size_t)arow[i] * lda + kbase + akc[i]);
    #pragma unroll
    for (int i = 0; i < 8; ++i)
        rb[i] = *(const bf16x8*)(Bm + (size_t)(n0 + brow[i]) * ldb + kbase + bkc[i]);
    #pragma unroll
    for (int i = 0; i < NA; ++i)
        *(bf16x8*)(As + arow[i] * LROW + akc[i]) = ra[i];
    #pragma unroll
    for (int i = 0; i < 8; ++i)
        *(bf16x8*)(Bs + brow[i] * LROW + bkc[i]) = rb[i];
    __syncthreads();

    for (int kt = 0; kt < nk; ++kt) {
        if (kt + 1 < nk) {
            int kb = kbase + (kt + 1) * KT;
            #pragma unroll
            for (int i = 0; i < NA; ++i)
                ra[i] = *(const bf16x8*)(A + (size_t)arow[i] * lda + kb + akc[i]);
            #pragma unroll
            for (int i = 0; i < 8; ++i)
                rb[i] = *(const bf16x8*)(Bm + (size_t)(n0 + brow[i]) * ldb + kb + bkc[i]);
        }
        #pragma unroll
        for (int ks = 0; ks < 4; ++ks) {
            bf16x8 af[MI], bfv[4];
            const int ko = ks * 32 + fk;
            #pragma unroll
            for (int mi = 0; mi < MI; ++mi)
                af[mi] = *(const bf16x8*)(As + (wm + mi * 16 + fr) * LROW + ko);
            #pragma unroll
            for (int ni = 0; ni < 4; ++ni)
                bfv[ni] = *(const bf16x8*)(Bs + (wn + ni * 16 + fr) * LROW + ko);
            #pragma unroll
            for (int mi = 0; mi < MI; ++mi)
                #pragma unroll
                for (int ni = 0; ni < 4; ++ni)
                    acc[mi][ni] = __builtin_amdgcn_mfma_f32_16x16x32_bf16(
                        af[mi], bfv[ni], acc[mi][ni], 0, 0, 0);
        }
        __syncthreads();
        if (kt + 1 < nk) {
            #pragma unroll
            for (int i = 0; i < NA; ++i)
                *(bf16x8*)(As + arow[i] * LROW + akc[i]) = ra[i];
            #pragma unroll
            for (int i = 0; i < 8; ++i)
                *(bf16x8*)(Bs + brow[i] * LROW + bkc[i]) = rb[i];
            __syncthreads();
        }
    }
}

// ---------- prep: bf16 conversions + yE one-hot ----------
__global__ __launch_bounds__(256) void k_prep(
    const float* __restrict__ W_ih, const float* __restrict__ W_hh,
    const float* __restrict__ W_out, const float* __restrict__ noise,
    const float* __restrict__ W_init, const float* __restrict__ emb,
    ushort* __restrict__ WihB, ushort* __restrict__ WhhB, ushort* __restrict__ WoutB,
    ushort* __restrict__ noiseB, ushort* __restrict__ WinitB,
    ushort* __restrict__ embB, ushort* __restrict__ yE)
{
    const int tg = blockIdx.x * 256 + threadIdx.x;
    const int NTH = gridDim.x * 256;
    for (int i = tg; i < G3H * Eq / 4; i += NTH) {
        float4 f = *(const float4*)(W_ih + (size_t)i * 4);
        *(ushort4*)(WihB + (size_t)i * 4) =
            make_ushort4(f2bf(f.x), f2bf(f.y), f2bf(f.z), f2bf(f.w));
    }
    for (int i = tg; i < G3H * Hq / 4; i += NTH) {
        float4 f = *(const float4*)(W_hh + (size_t)i * 4);
        *(ushort4*)(WhhB + (size_t)i * 4) =
            make_ushort4(f2bf(f.x), f2bf(f.y), f2bf(f.z), f2bf(f.w));
    }
    for (int i = tg; i < VP * (Hq / 4); i += NTH) {
        int v = i >> 7, h4 = (i & 127) << 2;
        ushort4 o = make_ushort4(0, 0, 0, 0);
        if (v < Vq) {
            float4 f = *(const float4*)(W_out + (size_t)v * Hq + h4);
            o = make_ushort4(f2bf(f.x), f2bf(f.y), f2bf(f.z), f2bf(f.w));
        }
        *(ushort4*)(WoutB + (size_t)v * Hq + h4) = o;
    }
    for (int i = tg; i < VP * (Eq / 4); i += NTH) {
        int v = i >> 6, e4 = (i & 63) << 2;
        ushort4 o = make_ushort4(0, 0, 0, 0);
        if (v < Vq) {
            float4 f = *(const float4*)(emb + (size_t)v * Eq + e4);
            o = make_ushort4(f2bf(f.x), f2bf(f.y), f2bf(f.z), f2bf(f.w));
        }
        *(ushort4*)(embB + (size_t)v * Eq + e4) = o;
    }
    for (int i = tg; i < Bq * Lq / 4; i += NTH) {
        float4 f = *(const float4*)(noise + (size_t)i * 4);
        *(ushort4*)(noiseB + (size_t)i * 4) =
            make_ushort4(f2bf(f.x), f2bf(f.y), f2bf(f.z), f2bf(f.w));
    }
    for (int i = tg; i < Hq * Lq / 4; i += NTH) {
        float4 f = *(const float4*)(W_init + (size_t)i * 4);
        *(ushort4*)(WinitB + (size_t)i * 4) =
            make_ushort4(f2bf(f.x), f2bf(f.y), f2bf(f.z), f2bf(f.w));
    }
    for (int i = tg; i < Bq * (VP / 4); i += NTH) {
        int v4 = i % (VP / 4);
        ushort4 o = (v4 == 0) ? make_ushort4(0x3F80, 0, 0, 0)
                              : make_ushort4(0, 0, 0, 0);
        *(ushort4*)(yE + (size_t)i * 4) = o;
    }
}

// ---------- WcombT (480 blk) + h0 (4 blk) ----------
__global__ __launch_bounds__(256) void k_wh0(
    const ushort* __restrict__ WihB, const ushort* __restrict__ embB,
    const ushort* __restrict__ noiseB, const ushort* __restrict__ WinitB,
    const float* __restrict__ b_init,
    ushort* __restrict__ WcombT, float* __restrict__ h0, ushort* __restrict__ hB0)
{
    __shared__ __align__(16) ushort As[128 * LROW];
    __shared__ __align__(16) ushort Bs[128 * LROW];
    const int bid = blockIdx.x;
    const int lane = threadIdx.x & 63;
    const int w = threadIdx.x >> 6;
    const int wm = (w >> 1) * 64, wn = (w & 1) * 64;
    const int fr = lane & 15, hi = lane >> 4;
    f32x4 acc[4][4];
    #pragma unroll
    for (int mi = 0; mi < 4; ++mi)
        #pragma unroll
        for (int ni = 0; ni < 4; ++ni) acc[mi][ni] = (f32x4){0.f,0.f,0.f,0.f};
    if (bid < 480) {
        int mt = bid / 40, nt = bid % 40;
        macT<4>(acc, WihB + (size_t)mt * 128 * Eq, Eq, embB, Eq,
                nt * 128, 0, Eq, As, Bs);
        #pragma unroll
        for (int mi = 0; mi < 4; ++mi)
            #pragma unroll
            for (int ni = 0; ni < 4; ++ni) {
                int n = nt * 128 + wn + ni * 16 + fr;
                #pragma unroll
                for (int r = 0; r < 4; ++r) {
                    int m = mt * 128 + wm + mi * 16 + hi * 4 + r;
                    WcombT[(size_t)m * VP + n] = f2bf(acc[mi][ni][r]);
                }
            }
    } else {
        int n0 = (bid - 480) * 128;
        macT<4>(acc, noiseB, Lq, WinitB, Lq, n0, 0, Lq, As, Bs);
        #pragma unroll
        for (int mi = 0; mi < 4; ++mi)
            #pragma unroll
            for (int ni = 0; ni < 4; ++ni) {
                int n = n0 + wn + ni * 16 + fr;
                float bv = b_init[n];
                #pragma unroll
                for (int r = 0; r < 4; ++r) {
                    int m = wm + mi * 16 + hi * 4 + r;
                    float v = acc[mi][ni][r] + bv;
                    h0[(size_t)m * Hq + n] = v;
                    hB0[(size_t)m * Hq + n] = f2bf(v);
                }
            }
    }
}

// ---------- K1: gi (192 blk, MI=2, bf16 z-partials) [+ gh at t==0 only] ----------
// bid = nt*16 + mh*8 + z  => blocks sharing (nt,z) (same B slice) are bid,bid+8:
// same XCD under %8 round-robin; all blocks on XCD x have z==x, so each XCD's
// WcombT working set is 1536x640x2B ~= 1.97 MB < 4 MB per-XCD L2.
__global__ __launch_bounds__(256) void k_gi(
    const ushort* __restrict__ yE, const ushort* __restrict__ WcombT,
    const ushort* __restrict__ hB_old, const ushort* __restrict__ WhhB,
    ushort* __restrict__ gip, ushort* __restrict__ ghp, int t)
{
    __shared__ __align__(16) ushort As[64 * LROW];
    __shared__ __align__(16) ushort Bs[128 * LROW];
    const int bid = blockIdx.x;
    const int lane = threadIdx.x & 63, w = threadIdx.x >> 6;
    const int fr = lane & 15, hi = lane >> 4;
    const int wm = (w >> 1) * 32, wn = (w & 1) * 64;
    f32x4 acc[2][4];
    #pragma unroll
    for (int mi = 0; mi < 2; ++mi)
        #pragma unroll
        for (int ni = 0; ni < 4; ++ni) acc[mi][ni] = (f32x4){0.f,0.f,0.f,0.f};
    if (bid < 192) {
        const int nt = bid >> 4, rem = bid & 15;
        const int mh = rem >> 3, z = rem & 7;
        const int n0 = nt * 128;
        macT<2>(acc, yE + (size_t)mh * 64 * VP, VP, WcombT, VP,
                n0, z * 640, 640, As, Bs);
        ushort* C = gip + (size_t)z * (Bq * G3H);
        #pragma unroll
        for (int mi = 0; mi < 2; ++mi)
            #pragma unroll
            for (int ni = 0; ni < 4; ++ni) {
                int n = n0 + wn + ni * 16 + fr;
                #pragma unroll
                for (int r = 0; r < 4; ++r) {
                    int m = mh * 64 + wm + mi * 16 + hi * 4 + r;
                    C[(size_t)m * G3H + n] = f2bf(acc[mi][ni][r]);
                }
            }
    } else if (t == 0) {
        // gh for t=0 (later steps get gh from k_logits of step t-1)
        const int j = bid - 192;
        const int nt = j >> 2, rem = j & 3;
        const int mh = rem >> 1, kc = rem & 1;
        const int n0 = nt * 128;
        macT<2>(acc, hB_old + (size_t)mh * 64 * Hq, Hq, WhhB, Hq,
                n0, kc * 256, 256, As, Bs);
        ushort* C = ghp + (size_t)kc * (Bq * G3H);
        #pragma unroll
        for (int mi = 0; mi < 2; ++mi)
            #pragma unroll
            for (int ni = 0; ni < 4; ++ni) {
                int n = n0 + wn + ni * 16 + fr;
                #pragma unroll
                for (int r = 0; r < 4; ++r) {
                    int m = mh * 64 + wm + mi * 16 + hi * 4 + r;
                    C[(size_t)m * G3H + n] = f2bf(acc[mi][ni][r]);
                }
            }
    }
}

// ---------- K2: gates (256 blk; invS fold; bf16 partials) ----------
__global__ __launch_bounds__(256) void k_gates(
    const ushort* __restrict__ gip, const ushort* __restrict__ ghp,
    const float* __restrict__ b_ih, const float* __restrict__ b_hh,
    const float* __restrict__ h_old, const float* __restrict__ esumAll,
    float* __restrict__ h_new, ushort* __restrict__ hB_new, int t)
{
    __shared__ float sred[64];
    const int tid = threadIdx.x;
    const int e = blockIdx.x * 256 + tid;   // 65536 total
    const int b = e >> 9, i = e & 511;
    if (t > 0) {
        if (tid < 40) sred[tid] = esumAll[(size_t)(t - 1) * 5120 + tid * 128 + b];
        __syncthreads();
        if (tid == 0) {
            float S = 0.f;
            #pragma unroll
            for (int nt = 0; nt < 40; ++nt) S += sred[nt];
            sred[63] = 1.0f / S;
        }
        __syncthreads();
    } else {
        if (tid == 0) sred[63] = 1.0f;
        __syncthreads();
    }
    const float invS = sred[63];

    const size_t o = (size_t)b * G3H + i;
    float xr = 0.f, xz = 0.f, xn = 0.f;
    #pragma unroll
    for (int z = 0; z < 8; ++z) {
        const ushort* gp = gip + (size_t)z * (Bq * G3H) + o;
        xr += bf2f(gp[0]); xz += bf2f(gp[Hq]); xn += bf2f(gp[2 * Hq]);
    }
    xr = xr * invS + b_ih[i];
    xz = xz * invS + b_ih[Hq + i];
    xn = xn * invS + b_ih[2 * Hq + i];
    const ushort* h0p = ghp + o;
    const ushort* h1p = ghp + (size_t)(Bq * G3H) + o;
    float hr = b_hh[i] + bf2f(h0p[0]) + bf2f(h1p[0]);
    float hz = b_hh[Hq + i] + bf2f(h0p[Hq]) + bf2f(h1p[Hq]);
    float hn = b_hh[2 * Hq + i] + bf2f(h0p[2 * Hq]) + bf2f(h1p[2 * Hq]);
    float r = 1.f / (1.f + expf(-(xr + hr)));
    float zz = 1.f / (1.f + expf(-(xz + hz)));
    float nn = tanhf(xn + r * hn);
    float hv = (1.f - zz) * nn + zz * h_old[e];
    h_new[e] = hv;
    hB_new[e] = f2bf(hv);
}

// ---------- K3: logits+gumbel+exp (160 blk, MI=1) || gh(t+1) (48 blk, MI=2)
//             || norm out[t-1] (64 blk) ----------
// gh(t+1) only needs hB_new(t), which k_gates already wrote; norm(t-1) only
// needs esum(t-1). Both fill CUs left idle by the 160 logits blocks, and they
// come OFF the critical k_gi kernel of the next step.
__global__ __launch_bounds__(256) void k_logits(
    const ushort* __restrict__ hB, const ushort* __restrict__ WoutB,
    const ushort* __restrict__ WhhB,
    const float* __restrict__ b_out, const float* __restrict__ gum,
    const float* __restrict__ temp,
    float* __restrict__ out, ushort* __restrict__ yE,
    float* __restrict__ esumAll, ushort* __restrict__ ghp, int t)
{
    __shared__ __align__(16) ushort As[64 * LROW];
    __shared__ __align__(16) ushort Bs[128 * LROW];
    const int bid = blockIdx.x;
    const int tid = threadIdx.x;
    const int lane = tid & 63, w = tid >> 6;
    const int fr = lane & 15, hi = lane >> 4;
    if (bid < 160) {
        const int nt = bid >> 2;                 // 40 N-tiles
        const int mbase = (bid & 3) * 32;        // 4 M-quarters
        const int n0 = nt * 128;
        const int wm = (w >> 1) * 16, wn = (w & 1) * 64;
        const float inv_tau = 1.0f / temp[0];
        f32x4 acc[1][4];
        #pragma unroll
        for (int ni = 0; ni < 4; ++ni) acc[0][ni] = (f32x4){0.f,0.f,0.f,0.f};
        macT<1>(acc, hB + (size_t)mbase * Hq, Hq, WoutB, Hq, n0, 0, Hq, As, Bs);

        float psum[4] = {0.f, 0.f, 0.f, 0.f};
        #pragma unroll
        for (int ni = 0; ni < 4; ++ni) {
            int v = n0 + wn + ni * 16 + fr;
            bool valid = v < Vq;
            float bo = valid ? b_out[v] : 0.f;
            #pragma unroll
            for (int r = 0; r < 4; ++r) {
                int m = mbase + wm + hi * 4 + r;
                float ev = 0.f;
                if (valid) {
                    float g = gum[(size_t)m * Vq + v];
                    ev = expf((acc[0][ni][r] + bo + g) * inv_tau);
                    out[(size_t)m * Tq * Vq + (size_t)t * Vq + v] = ev;
                }
                yE[(size_t)m * VP + v] = f2bf(ev);
                psum[r] += ev;
            }
        }
        float* redbuf = (float*)As;   // safe: macT ended with __syncthreads
        #pragma unroll
        for (int r = 0; r < 4; ++r) {
            float s = psum[r];
            s += __shfl_xor(s, 1); s += __shfl_xor(s, 2);
            s += __shfl_xor(s, 4); s += __shfl_xor(s, 8);
            if (fr == 0)
                redbuf[((wm + hi * 4 + r) << 1) | (wn >> 6)] = s;
        }
        __syncthreads();
        if (tid < 32)
            esumAll[(size_t)t * 5120 + n0 + mbase + tid]
                = redbuf[tid * 2] + redbuf[tid * 2 + 1];
    } else if (bid < 208) {
        // gh for step t+1 using hB (= hB_new(t) = hB_old(t+1))
        const int j = bid - 160;
        const int nt = j >> 2, rem = j & 3;
        const int mh = rem >> 1, kc = rem & 1;
        const int n0 = nt * 128;
        const int wm = (w >> 1) * 32, wn = (w & 1) * 64;
        f32x4 acc[2][4];
        #pragma unroll
        for (int mi = 0; mi < 2; ++mi)
            #pragma unroll
            for (int ni = 0; ni < 4; ++ni) acc[mi][ni] = (f32x4){0.f,0.f,0.f,0.f};
        macT<2>(acc, hB + (size_t)mh * 64 * Hq, Hq, WhhB, Hq,
                n0, kc * 256, 256, As, Bs);
        ushort* C = ghp + (size_t)kc * (Bq * G3H);
        #pragma unroll
        for (int mi = 0; mi < 2; ++mi)
            #pragma unroll
            for (int ni = 0; ni < 4; ++ni) {
                int n = n0 + wn + ni * 16 + fr;
                #pragma unroll
                for (int r = 0; r < 4; ++r) {
                    int m = mh * 64 + wm + mi * 16 + hi * 4 + r;
                    C[(size_t)m * G3H + n] = f2bf(acc[mi][ni][r]);
                }
            }
    } else if (t > 0) {
        // normalize out[:, t-1, :]: 64 blocks x 2 rows
        #pragma unroll
        for (int j = 0; j < 2; ++j) {
            int b = (bid - 208) * 2 + j;
            float S = 0.f;
            #pragma unroll 8
            for (int nt2 = 0; nt2 < 40; ++nt2)
                S += esumAll[(size_t)(t - 1) * 5120 + nt2 * 128 + b];
            float inv = 1.0f / S;
            float* orow = out + ((size_t)b * Tq + (t - 1)) * Vq;
            #pragma unroll
            for (int i = 0; i < 20; ++i) {
                int v = tid + i * 256;
                if (v < Vq) orow[v] *= inv;
            }
        }
    }
}

// ---------- tail: normalize out[:, T-1, :] ----------
__global__ __launch_bounds__(256) void k_tail(
    float* __restrict__ out, const float* __restrict__ esumAll)
{
    const int tid = threadIdx.x;
    #pragma unroll
    for (int j = 0; j < 4; ++j) {
        int b = blockIdx.x * 4 + j;
        float S = 0.f;
        #pragma unroll 8
        for (int nt = 0; nt < 40; ++nt)
            S += esumAll[(size_t)(Tq - 1) * 5120 + nt * 128 + b];
        float inv = 1.0f / S;
        float* orow = out + ((size_t)b * Tq + (Tq - 1)) * Vq;
        #pragma unroll
        for (int i = 0; i < 20; ++i) {
            int v = tid + i * 256;
            if (v < Vq) orow[v] *= inv;
        }
    }
}

extern "C" void kernel_launch(void* const* d_in, const int* in_sizes, int n_in,
                              void* d_out, int out_size, void* d_ws, size_t ws_size,
                              hipStream_t stream)
{
    const float* noise   = (const float*)d_in[0];
    const float* gumbel  = (const float*)d_in[1];
    const float* temp    = (const float*)d_in[2];
    const float* W_init  = (const float*)d_in[3];
    const float* b_init  = (const float*)d_in[4];
    const float* emb     = (const float*)d_in[5];
    const float* W_ih    = (const float*)d_in[6];
    const float* W_hh    = (const float*)d_in[7];
    const float* b_ih    = (const float*)d_in[8];
    const float* b_hh    = (const float*)d_in[9];
    const float* W_out   = (const float*)d_in[10];
    const float* b_out   = (const float*)d_in[11];
    float* out = (float*)d_out;

    float* fbase   = (float*)d_ws;
    float* h       = fbase;                       // 2 * 65536
    float* esumAll = h + 2 * 65536;               // 128 * 5120 = 655360
    ushort* ub     = (ushort*)(esumAll + 655360);
    ushort* gip    = ub;                          // 8 * 196608 = 1572864
    ushort* ghp    = gip + 1572864;               // 2 * 196608 = 393216
    ushort* embB   = ghp + 393216;                // 1310720
    ushort* WihB   = embB + 1310720;              // 393216
    ushort* WhhB   = WihB + 393216;               // 786432
    ushort* WoutB  = WhhB + 786432;               // 2621440
    ushort* WcombT = WoutB + 2621440;             // 7864320
    ushort* noiseB = WcombT + 7864320;            // 16384
    ushort* WinitB = noiseB + 16384;              // 65536
    ushort* hB     = WinitB + 65536;              // 2 * 65536
    ushort* yE     = hB + 2 * 65536;              // 655360

    k_prep<<<dim3(512), dim3(256), 0, stream>>>(
        W_ih, W_hh, W_out, noise, W_init, emb,
        WihB, WhhB, WoutB, noiseB, WinitB, embB, yE);
    k_wh0<<<dim3(484), dim3(256), 0, stream>>>(
        WihB, embB, noiseB, WinitB, b_init, WcombT, h, hB);

    for (int t = 0; t < Tq; ++t) {
        float* h_old = h + (size_t)(t & 1) * 65536;
        float* h_new = h + (size_t)((t + 1) & 1) * 65536;
        ushort* hB_old = hB + (size_t)(t & 1) * 65536;
        ushort* hB_new = hB + (size_t)((t + 1) & 1) * 65536;

        k_gi<<<dim3(t == 0 ? 240 : 192), dim3(256), 0, stream>>>(
            yE, WcombT, hB_old, WhhB, gip, ghp, t);
        k_gates<<<dim3(256), dim3(256), 0, stream>>>(
            gip, ghp, b_ih, b_hh, h_old, esumAll, h_new, hB_new, t);
        k_logits<<<dim3(272), dim3(256), 0, stream>>>(
            hB_new, WoutB, WhhB, b_out, gumbel + (size_t)t * Bq * Vq, temp,
            out, yE, esumAll, ghp, t);
    }
    k_tail<<<dim3(32), dim3(256), 0, stream>>>(out, esumAll);
}